// Round 2
// baseline (559.851 us; speedup 1.0000x reference)
//
#include <hip/hip_runtime.h>

#define N_OCC   20000
#define N_SKILL 50000
#define N_EDGE  600000
#define D_IN    256
#define HID     128
#define OUT_F   64

typedef short bf16x8 __attribute__((ext_vector_type(8)));
typedef float f32x4  __attribute__((ext_vector_type(4)));

__device__ __forceinline__ float bf2f(unsigned short u){
  return __uint_as_float(((unsigned)u) << 16);
}
__device__ __forceinline__ unsigned f2bf_bits(float f){
  unsigned i = __float_as_uint(f);
  return (i + 0x7fffu + ((i >> 16) & 1u)) >> 16;   // RNE
}
__device__ __forceinline__ unsigned f2bf_bits_u(unsigned i){
  return (i + 0x7fffu + ((i >> 16) & 1u)) >> 16;   // RNE from raw f32 bits
}
__device__ __forceinline__ unsigned short f2bf(float f){ return (unsigned short)f2bf_bits(f); }

// ---------- wire-dtype detection ----------
// Interpret first 1024 shorts of x_occ as bf16. If the wire is f32, half of
// these are f32 low-mantissa halves -> random exponent field -> ~12% have
// exp >= 0xE0. If wire is bf16 (N(0,1) data), none do.
__global__ void k_detect(const unsigned short* __restrict__ x, int* __restrict__ flag){
  int lane = threadIdx.x & 63;
  int cnt = 0;
  for (int i = lane; i < 1024; i += 64){
    unsigned e = ((unsigned)x[i] >> 7) & 0xFFu;
    if (e >= 0xE0u) cnt++;
  }
  #pragma unroll
  for (int s = 1; s < 64; s <<= 1) cnt += __shfl_xor(cnt, s, 64);
  if (lane == 0) *flag = (cnt >= 8) ? 1 : 0;   // 1 => wire is f32
}

// ---------- canonicalize all float tensors to bf16 ----------
#define NT_CONV 18
struct ConvTable {
  const void*     src[NT_CONV];
  unsigned short* dst[NT_CONV];
  int             n[NT_CONV];
  int             blk_off[NT_CONV + 1];   // cumulative blocks (2048 elems/block)
};

__global__ void k_convert(ConvTable t, const int* __restrict__ flag){
  int isf32 = *flag;
  int b = blockIdx.x;
  int ti = 0;
  while (ti < NT_CONV - 1 && b >= t.blk_off[ti + 1]) ti++;
  int lb = b - t.blk_off[ti];
  int i = (lb * 256 + (int)threadIdx.x) * 8;     // element index (8 per thread)
  if (i >= t.n[ti]) return;
  unsigned short* dst = t.dst[ti];
  if (isf32){
    const float* s = (const float*)t.src[ti];
    uint4 lo = *(const uint4*)(s + i);
    uint4 hi = *(const uint4*)(s + i + 4);
    uint4 o;
    o.x = f2bf_bits_u(lo.x) | (f2bf_bits_u(lo.y) << 16);
    o.y = f2bf_bits_u(lo.z) | (f2bf_bits_u(lo.w) << 16);
    o.z = f2bf_bits_u(hi.x) | (f2bf_bits_u(hi.y) << 16);
    o.w = f2bf_bits_u(hi.z) | (f2bf_bits_u(hi.w) << 16);
    *(uint4*)(dst + i) = o;
  } else {
    *(uint4*)(dst + i) = *(const uint4*)((const unsigned short*)t.src[ti] + i);
  }
}

// ---------- transpose all 10 canonical weight matrices W[K][N] -> WT[N][K] ----------
__global__ void k_transpose_all(
    const unsigned short* pWo, unsigned short* tWo,   // 256x128
    const unsigned short* pWs, unsigned short* tWs,   // 256x128
    const unsigned short* w2,  unsigned short* t2,    // 128x128
    const unsigned short* w3,  unsigned short* t3,
    const unsigned short* w4,  unsigned short* t4,
    const unsigned short* w5,  unsigned short* t5,
    const unsigned short* w6,  unsigned short* t6,    // 128x64
    const unsigned short* w7,  unsigned short* t7,
    const unsigned short* w8,  unsigned short* t8,
    const unsigned short* w9,  unsigned short* t9)
{
  int idx = blockIdx.x * blockDim.x + threadIdx.x;
  const unsigned short* in; unsigned short* out; int K, N, base;
  if      (idx <  32768){ in=pWo; out=tWo; K=256; N=128; base=0; }
  else if (idx <  65536){ in=pWs; out=tWs; K=256; N=128; base=32768; }
  else if (idx <  81920){ in=w2;  out=t2;  K=128; N=128; base=65536; }
  else if (idx <  98304){ in=w3;  out=t3;  K=128; N=128; base=81920; }
  else if (idx < 114688){ in=w4;  out=t4;  K=128; N=128; base=98304; }
  else if (idx < 131072){ in=w5;  out=t5;  K=128; N=128; base=114688; }
  else if (idx < 139264){ in=w6;  out=t6;  K=128; N=64;  base=131072; }
  else if (idx < 147456){ in=w7;  out=t7;  K=128; N=64;  base=139264; }
  else if (idx < 155648){ in=w8;  out=t8;  K=128; N=64;  base=147456; }
  else if (idx < 163840){ in=w9;  out=t9;  K=128; N=64;  base=155648; }
  else return;
  int li = idx - base;
  int k = li / N, n = li - k * N;
  out[n * K + k] = in[li];
}

// ---------- degree histogram ----------
__global__ void k_degree(const int* __restrict__ eo, const int* __restrict__ es,
                         int* __restrict__ cnt_s, int* __restrict__ cnt_o)
{
  int i = blockIdx.x * blockDim.x + threadIdx.x;
  if (i < N_EDGE){
    atomicAdd(&cnt_s[es[i]], 1);
    atomicAdd(&cnt_o[eo[i]], 1);
  }
}

// ---------- single-block exclusive scan ----------
__global__ void k_excl_scan(const int* __restrict__ in, int* __restrict__ out, int n)
{
  __shared__ int wsum[16];
  __shared__ int carry_s;
  int tid = threadIdx.x;
  int lane = tid & 63;
  int wv = tid >> 6;
  if (tid == 0) carry_s = 0;
  __syncthreads();
  for (int base = 0; base < n; base += 1024){
    int i = base + tid;
    int v = (i < n) ? in[i] : 0;
    int x = v;
    #pragma unroll
    for (int s = 1; s < 64; s <<= 1){
      int t = __shfl_up(x, s, 64);
      if (lane >= s) x += t;
    }
    if (lane == 63) wsum[wv] = x;
    __syncthreads();
    int woff = 0;
    for (int w = 0; w < wv; ++w) woff += wsum[w];
    int excl = carry_s + woff + x - v;
    if (i < n) out[i] = excl;
    __syncthreads();
    if (tid == 1023) carry_s = excl + v;
    __syncthreads();
  }
  if (tid == 0) out[n] = carry_s;
}

// ---------- CSR fill ----------
__global__ void k_fill(const int* __restrict__ eo, const int* __restrict__ es,
                       const int* __restrict__ off_s, int* __restrict__ cur_s, int* __restrict__ csr_s,
                       const int* __restrict__ off_o, int* __restrict__ cur_o, int* __restrict__ csr_o)
{
  int i = blockIdx.x * blockDim.x + threadIdx.x;
  if (i < N_EDGE){
    int s = eo[i], d = es[i];
    int p = off_s[d] + atomicAdd(&cur_s[d], 1);
    csr_s[p] = s;
    int q = off_o[s] + atomicAdd(&cur_o[s], 1);
    csr_o[q] = d;
  }
}

// ---------- segment mean: one wave per dst node, 128 bf16 feats ----------
__launch_bounds__(256)
__global__ void k_seg_mean(const unsigned short* __restrict__ feat,
                           const int* __restrict__ off, const int* __restrict__ csr,
                           unsigned short* __restrict__ out, int n_dst)
{
  int gw = (int)((blockIdx.x * blockDim.x + threadIdx.x) >> 6);
  if (gw >= n_dst) return;
  int lane = threadIdx.x & 63;
  int r = lane >> 4;
  int c = lane & 15;
  int beg = off[gw], end = off[gw + 1];
  float acc[8];
  #pragma unroll
  for (int j = 0; j < 8; ++j) acc[j] = 0.0f;
  for (int e = beg + r; e < end; e += 4){
    int s = csr[e];
    uint4 v = *(const uint4*)(feat + ((size_t)s << 7) + (c << 3));
    acc[0] += __uint_as_float(v.x << 16); acc[1] += __uint_as_float(v.x & 0xffff0000u);
    acc[2] += __uint_as_float(v.y << 16); acc[3] += __uint_as_float(v.y & 0xffff0000u);
    acc[4] += __uint_as_float(v.z << 16); acc[5] += __uint_as_float(v.z & 0xffff0000u);
    acc[6] += __uint_as_float(v.w << 16); acc[7] += __uint_as_float(v.w & 0xffff0000u);
  }
  #pragma unroll
  for (int j = 0; j < 8; ++j){
    acc[j] += __shfl_xor(acc[j], 16, 64);
    acc[j] += __shfl_xor(acc[j], 32, 64);
  }
  if (r == 0){
    int cnt = end - beg;
    float inv = 1.0f / (float)(cnt > 0 ? cnt : 1);
    uint4 o;
    o.x = f2bf_bits(acc[0] * inv) | (f2bf_bits(acc[1] * inv) << 16);
    o.y = f2bf_bits(acc[2] * inv) | (f2bf_bits(acc[3] * inv) << 16);
    o.z = f2bf_bits(acc[4] * inv) | (f2bf_bits(acc[5] * inv) << 16);
    o.w = f2bf_bits(acc[6] * inv) | (f2bf_bits(acc[7] * inv) << 16);
    *(uint4*)(out + ((size_t)gw << 7) + (c << 3)) = o;
  }
}

// ---------- fused GEMM: C = act(A1@W1 + [A2@W2] + bias) ----------
// WT[n][k] row-major. Intermediate outputs always bf16; final outputs follow
// the wire flag (to_wire=1): f32 if *wire_flag else bf16. c_off = element offset.
template<int NCOLS>
__launch_bounds__(256)
__global__ void k_gemm(const unsigned short* __restrict__ A1,
                       const unsigned short* __restrict__ W1T, int K1,
                       const unsigned short* __restrict__ A2,
                       const unsigned short* __restrict__ W2T, int K2,
                       const unsigned short* __restrict__ bias,
                       void* __restrict__ C, size_t c_off,
                       int M, int do_relu,
                       int to_wire, const int* __restrict__ wire_flag)
{
  constexpr int NT = NCOLS / 16;
  constexpr int MW = 2;
  const int lane = threadIdx.x & 63;
  const int wv   = threadIdx.x >> 6;
  const int q    = lane >> 4;
  const int mr   = lane & 15;
  const int m0   = blockIdx.x * (4 * MW * 16) + wv * (MW * 16);
  const int koff = q * 8;

  f32x4 acc[MW][NT];
  #pragma unroll
  for (int mw = 0; mw < MW; ++mw)
    #pragma unroll
    for (int nt = 0; nt < NT; ++nt)
      #pragma unroll
      for (int j = 0; j < 4; ++j) acc[mw][nt][j] = 0.0f;

  for (int k0 = 0; k0 < K1; k0 += 32){
    bf16x8 a[MW], b[NT];
    #pragma unroll
    for (int mw = 0; mw < MW; ++mw){
      int row = m0 + mw * 16 + mr;
      if (row < M){
        a[mw] = *(const bf16x8*)(A1 + (size_t)row * K1 + k0 + koff);
      } else {
        #pragma unroll
        for (int j = 0; j < 8; ++j) a[mw][j] = 0;
      }
    }
    #pragma unroll
    for (int nt = 0; nt < NT; ++nt)
      b[nt] = *(const bf16x8*)(W1T + (size_t)(nt * 16 + mr) * K1 + k0 + koff);
    #pragma unroll
    for (int mw = 0; mw < MW; ++mw)
      #pragma unroll
      for (int nt = 0; nt < NT; ++nt)
        acc[mw][nt] = __builtin_amdgcn_mfma_f32_16x16x32_bf16(a[mw], b[nt], acc[mw][nt], 0, 0, 0);
  }

  if (A2 != nullptr){
    for (int k0 = 0; k0 < K2; k0 += 32){
      bf16x8 a[MW], b[NT];
      #pragma unroll
      for (int mw = 0; mw < MW; ++mw){
        int row = m0 + mw * 16 + mr;
        if (row < M){
          a[mw] = *(const bf16x8*)(A2 + (size_t)row * K2 + k0 + koff);
        } else {
          #pragma unroll
          for (int j = 0; j < 8; ++j) a[mw][j] = 0;
        }
      }
      #pragma unroll
      for (int nt = 0; nt < NT; ++nt)
        b[nt] = *(const bf16x8*)(W2T + (size_t)(nt * 16 + mr) * K2 + k0 + koff);
      #pragma unroll
      for (int mw = 0; mw < MW; ++mw)
        #pragma unroll
        for (int nt = 0; nt < NT; ++nt)
          acc[mw][nt] = __builtin_amdgcn_mfma_f32_16x16x32_bf16(a[mw], b[nt], acc[mw][nt], 0, 0, 0);
    }
  }

  const int wf = to_wire ? *wire_flag : 0;   // 1 => write f32
  #pragma unroll
  for (int mw = 0; mw < MW; ++mw){
    #pragma unroll
    for (int nt = 0; nt < NT; ++nt){
      int col = nt * 16 + mr;
      float bv = bf2f(bias[col]);
      #pragma unroll
      for (int r4 = 0; r4 < 4; ++r4){
        int row = m0 + mw * 16 + q * 4 + r4;
        if (row < M){
          float v = acc[mw][nt][r4] + bv;
          if (do_relu) v = fmaxf(v, 0.0f);
          size_t idx = c_off + (size_t)row * NCOLS + col;
          if (wf) ((float*)C)[idx] = v;
          else    ((unsigned short*)C)[idx] = f2bf(v);
        }
      }
    }
  }
}

extern "C" void kernel_launch(void* const* d_in, const int* in_sizes, int n_in,
                              void* d_out, int out_size, void* d_ws, size_t ws_size,
                              hipStream_t stream)
{
  const void* raw[20];
  for (int i = 0; i < 20; ++i) raw[i] = d_in[i];
  const int* edge_occ   = (const int*)d_in[2];
  const int* edge_skill = (const int*)d_in[3];

  char* ws = (char*)d_ws;
  size_t off = 0;
  auto alloc = [&](size_t bytes) -> char* {
    char* p = ws + off;
    off = (off + bytes + 255) & ~(size_t)255;
    return p;
  };

  int* wire_flag = (int*)alloc(4);

  // canonical bf16 copies of all float tensors (18 of them)
  static const int cn[NT_CONV] = {
    N_OCC * D_IN, N_SKILL * D_IN,                // x_occ, x_skill
    D_IN * HID, HID, D_IN * HID, HID,            // pW_occ, pb_occ, pW_skill, pb_skill
    HID * HID, HID, HID * HID,                   // c1_os_Wl, bl, Wr
    HID * HID, HID, HID * HID,                   // c1_so_Wl, bl, Wr
    HID * OUT_F, OUT_F, HID * OUT_F,             // c2_os_Wl, bl, Wr
    HID * OUT_F, OUT_F, HID * OUT_F              // c2_so_Wl, bl, Wr
  };
  static const int raw_idx[NT_CONV] = {0,1, 4,5,6,7, 8,9,10, 11,12,13, 14,15,16, 17,18,19};
  unsigned short* can[NT_CONV];
  for (int i = 0; i < NT_CONV; ++i) can[i] = (unsigned short*)alloc((size_t)cn[i] * 2);

  ConvTable ct;
  ct.blk_off[0] = 0;
  for (int i = 0; i < NT_CONV; ++i){
    ct.src[i] = raw[raw_idx[i]];
    ct.dst[i] = can[i];
    ct.n[i]   = cn[i];
    ct.blk_off[i + 1] = ct.blk_off[i] + (cn[i] + 2047) / 2048;
  }
  const int conv_blocks = ct.blk_off[NT_CONV];

  const unsigned short* c_xocc   = can[0];
  const unsigned short* c_xskill = can[1];
  const unsigned short* c_pWo = can[2],  *c_pbo = can[3];
  const unsigned short* c_pWs = can[4],  *c_pbs = can[5];
  const unsigned short* c1osWl = can[6], *c1osbl = can[7], *c1osWr = can[8];
  const unsigned short* c1soWl = can[9], *c1sobl = can[10], *c1soWr = can[11];
  const unsigned short* c2osWl = can[12], *c2osbl = can[13], *c2osWr = can[14];
  const unsigned short* c2soWl = can[15], *c2sobl = can[16], *c2soWr = can[17];

  // transposed weights
  unsigned short* wt_pocc   = (unsigned short*)alloc(32768 * 2);
  unsigned short* wt_pskill = (unsigned short*)alloc(32768 * 2);
  unsigned short* wt_c1osWl = (unsigned short*)alloc(16384 * 2);
  unsigned short* wt_c1osWr = (unsigned short*)alloc(16384 * 2);
  unsigned short* wt_c1soWl = (unsigned short*)alloc(16384 * 2);
  unsigned short* wt_c1soWr = (unsigned short*)alloc(16384 * 2);
  unsigned short* wt_c2osWl = (unsigned short*)alloc(8192 * 2);
  unsigned short* wt_c2osWr = (unsigned short*)alloc(8192 * 2);
  unsigned short* wt_c2soWl = (unsigned short*)alloc(8192 * 2);
  unsigned short* wt_c2soWr = (unsigned short*)alloc(8192 * 2);

  char* zero_base = alloc((size_t)(N_SKILL + N_OCC + N_SKILL + N_OCC) * 4);
  int* cnt_s = (int*)zero_base;
  int* cnt_o = cnt_s + N_SKILL;
  int* cur_s = cnt_o + N_OCC;
  int* cur_o = cur_s + N_SKILL;
  size_t zero_bytes = (size_t)(N_SKILL + N_OCC + N_SKILL + N_OCC) * 4;

  int* off_s = (int*)alloc((N_SKILL + 1) * 4);
  int* off_o = (int*)alloc((N_OCC + 1) * 4);
  int* csr_s = (int*)alloc((size_t)N_EDGE * 4);
  int* csr_o = (int*)alloc((size_t)N_EDGE * 4);

  unsigned short* h_occ   = (unsigned short*)alloc((size_t)N_OCC * HID * 2);
  unsigned short* h_skill = (unsigned short*)alloc((size_t)N_SKILL * HID * 2);
  unsigned short* mean_s  = (unsigned short*)alloc((size_t)N_SKILL * HID * 2);
  unsigned short* mean_o  = (unsigned short*)alloc((size_t)N_OCC * HID * 2);
  unsigned short* s1      = (unsigned short*)alloc((size_t)N_SKILL * HID * 2);
  unsigned short* o1      = (unsigned short*)alloc((size_t)N_OCC * HID * 2);

  const int EB = (N_EDGE + 255) / 256;
  const int G_OCC  = (N_OCC + 127) / 128;
  const int G_SKL  = (N_SKILL + 127) / 128;
  const int SM_SKL = (N_SKILL + 3) / 4;
  const int SM_OCC = (N_OCC + 3) / 4;

  hipMemsetAsync(zero_base, 0, zero_bytes, stream);

  k_detect<<<1, 64, 0, stream>>>((const unsigned short*)raw[0], wire_flag);
  k_convert<<<conv_blocks, 256, 0, stream>>>(ct, wire_flag);

  k_transpose_all<<<640, 256, 0, stream>>>(
      c_pWo, wt_pocc, c_pWs, wt_pskill,
      c1osWl, wt_c1osWl, c1osWr, wt_c1osWr,
      c1soWl, wt_c1soWl, c1soWr, wt_c1soWr,
      c2osWl, wt_c2osWl, c2osWr, wt_c2osWr,
      c2soWl, wt_c2soWl, c2soWr, wt_c2soWr);

  k_degree<<<EB, 256, 0, stream>>>(edge_occ, edge_skill, cnt_s, cnt_o);
  k_excl_scan<<<1, 1024, 0, stream>>>(cnt_s, off_s, N_SKILL);
  k_excl_scan<<<1, 1024, 0, stream>>>(cnt_o, off_o, N_OCC);
  k_fill<<<EB, 256, 0, stream>>>(edge_occ, edge_skill,
                                 off_s, cur_s, csr_s,
                                 off_o, cur_o, csr_o);

  // input projections + relu
  k_gemm<128><<<G_OCC, 256, 0, stream>>>(c_xocc, wt_pocc, D_IN, nullptr, nullptr, 0,
                                         c_pbo, h_occ, 0, N_OCC, 1, 0, wire_flag);
  k_gemm<128><<<G_SKL, 256, 0, stream>>>(c_xskill, wt_pskill, D_IN, nullptr, nullptr, 0,
                                         c_pbs, h_skill, 0, N_SKILL, 1, 0, wire_flag);

  // conv1 aggregation
  k_seg_mean<<<SM_SKL, 256, 0, stream>>>(h_occ, off_s, csr_s, mean_s, N_SKILL);
  k_seg_mean<<<SM_OCC, 256, 0, stream>>>(h_skill, off_o, csr_o, mean_o, N_OCC);

  // conv1 linear
  k_gemm<128><<<G_SKL, 256, 0, stream>>>(mean_s, wt_c1osWl, HID, h_skill, wt_c1osWr, HID,
                                         c1osbl, s1, 0, N_SKILL, 1, 0, wire_flag);
  k_gemm<128><<<G_OCC, 256, 0, stream>>>(mean_o, wt_c1soWl, HID, h_occ, wt_c1soWr, HID,
                                         c1sobl, o1, 0, N_OCC, 1, 0, wire_flag);

  // conv2 aggregation
  k_seg_mean<<<SM_SKL, 256, 0, stream>>>(o1, off_s, csr_s, mean_s, N_SKILL);
  k_seg_mean<<<SM_OCC, 256, 0, stream>>>(s1, off_o, csr_o, mean_o, N_OCC);

  // conv2 linear -> d_out (o2 at element offset 0, s2 after it)
  k_gemm<64><<<G_SKL, 256, 0, stream>>>(mean_s, wt_c2osWl, HID, s1, wt_c2osWr, HID,
                                        c2osbl, d_out, (size_t)N_OCC * OUT_F, N_SKILL, 0, 1, wire_flag);
  k_gemm<64><<<G_OCC, 256, 0, stream>>>(mean_o, wt_c2soWl, HID, o1, wt_c2soWr, HID,
                                        c2sobl, d_out, 0, N_OCC, 0, 1, wire_flag);
}